// Round 1
// baseline (2114.942 us; speedup 1.0000x reference)
//
#include <hip/hip_runtime.h>
#include <math.h>

#define Hh 128
#define Ww 128
#define HW (128*128)
#define CIN_OFF 196
#define COFF 432

// ---------------- kernel 0: transpose dc_weight [64][128][9] -> wT[j=ci*9+k][64] ----------
__global__ __launch_bounds__(256) void k_transpose_w(const float* __restrict__ dcw,
                                                     float* __restrict__ wT) {
  int idx = blockIdx.x * 256 + threadIdx.x;
  if (idx < 64 * 1152) {
    int co = idx / 1152;
    int j  = idx - co * 1152;
    wT[j * 64 + co] = dcw[idx];
  }
}

// ---------------- kernel 1: 196 -> 432 conv3x3 + fused activation/flow-add ----------------
// grid: (W/64=2, H=128, B*18=36), block 256.
// Each block: 1 row, 64 w-pixels, 24 output channels (4 waves x 6 co/thread).
__global__ __launch_bounds__(256) void k_offconv(
    const float* __restrict__ extra, const float* __restrict__ f1, const float* __restrict__ f2,
    const float* __restrict__ w_off, const float* __restrict__ b_off,
    float* __restrict__ off_buf, float* __restrict__ mask_buf) {
  const int wt  = blockIdx.x;
  const int h   = blockIdx.y;
  const int bz  = blockIdx.z;
  const int b   = bz / 18;
  const int cot = bz - b * 18;
  const int wl  = (int)threadIdx.x & 63;
  const int w   = wt * 64 + wl;
  int co_base = cot * 24 + (((int)threadIdx.x >> 6) * 6);
  co_base = __builtin_amdgcn_readfirstlane(co_base);  // wave-uniform -> scalar weight loads

  float acc[6];
#pragma unroll
  for (int i = 0; i < 6; ++i) acc[i] = b_off[co_base + i];

  for (int ci = 0; ci < CIN_OFF; ++ci) {
    const float* xp;
    if (ci < 192)      xp = extra + (size_t)(b * 192 + ci) * HW;
    else if (ci < 194) xp = f1 + (size_t)(b * 2 + (ci - 192)) * HW;
    else               xp = f2 + (size_t)(b * 2 + (ci - 194)) * HW;

    float wv[6][9];
#pragma unroll
    for (int i = 0; i < 6; ++i) {
      const float* wp = w_off + ((size_t)(co_base + i) * CIN_OFF + ci) * 9;
#pragma unroll
      for (int kk = 0; kk < 9; ++kk) wv[i][kk] = wp[kk];
    }

#pragma unroll
    for (int r = 0; r < 3; ++r) {
      const int gh = h - 1 + r;
      const bool vr = ((unsigned)gh < (unsigned)Hh);
      const float* xr = xp + gh * Ww;
#pragma unroll
      for (int c = 0; c < 3; ++c) {
        const int gw = w - 1 + c;
        float xv = (vr && ((unsigned)gw < (unsigned)Ww)) ? xr[gw] : 0.f;
#pragma unroll
        for (int i = 0; i < 6; ++i) acc[i] = fmaf(xv, wv[i][r * 3 + c], acc[i]);
      }
    }
  }

  const int hwp = h * Ww + w;
#pragma unroll
  for (int i = 0; i < 6; ++i) {
    const int co = co_base + i;
    const float v = acc[i];
    if (co < 288) {
      const float* fl = (co < 144) ? f1 : f2;
      // flow channel flip: comp 0 (dy) gets flow[1], comp 1 (dx) gets flow[0]
      const float add = fl[(size_t)(b * 2 + ((co & 1) ^ 1)) * HW + hwp];
      off_buf[(size_t)(b * 288 + co) * HW + hwp] = 10.f * tanhf(v) + add;
    } else {
      mask_buf[(size_t)(b * 144 + (co - 288)) * HW + hwp] = 1.f / (1.f + expf(-v));
    }
  }
}

// ---------------- kernel 2: modulated deformable conv ------------------------------------
// grid: (W/4=32, H=128, B=2), block 256.
// phase 1: sample 4 pixels x 16 groups x 9 taps x 8 ch into LDS (mask folded in)
// phase 2: per pixel out[64] = wT[1152][64]^T . sm[1152] + bias
__global__ __launch_bounds__(256) void k_deform(
    const float* __restrict__ fp, const float* __restrict__ fn2,
    const float* __restrict__ off_buf, const float* __restrict__ mask_buf,
    const float* __restrict__ wT, const float* __restrict__ dc_bias,
    float* __restrict__ out) {
  __shared__ float sm[4 * 1152];
  const int w0  = blockIdx.x * 4;
  const int h   = blockIdx.y;
  const int b   = blockIdx.z;
  const int tid = (int)threadIdx.x;

  for (int p = tid; p < 576; p += 256) {
    const int pix = p / 144;
    const int r   = p - pix * 144;
    const int g   = r / 9;
    const int k   = r - g * 9;
    const int w   = w0 + pix;
    const int hw  = h * Ww + w;
    const float oy = off_buf[(size_t)(b * 288 + g * 18 + k * 2 + 0) * HW + hw];
    const float ox = off_buf[(size_t)(b * 288 + g * 18 + k * 2 + 1) * HW + hw];
    const float m  = mask_buf[(size_t)(b * 144 + g * 9 + k) * HW + hw];
    const int ki = k / 3, kj = k - (k / 3) * 3;
    const float py = (float)(h - 1 + ki) + oy;
    const float px = (float)(w - 1 + kj) + ox;
    const float y0f = floorf(py), x0f = floorf(px);
    const int y0 = (int)y0f, x0 = (int)x0f;
    const float ly = py - y0f, lx = px - x0f;
    const float hy = 1.f - ly, hx = 1.f - lx;
    const int y1 = y0 + 1, x1 = x0 + 1;
    const bool vy0 = (unsigned)y0 < (unsigned)Hh, vy1 = (unsigned)y1 < (unsigned)Hh;
    const bool vx0 = (unsigned)x0 < (unsigned)Ww, vx1 = (unsigned)x1 < (unsigned)Ww;
    const float w00 = (vy0 && vx0) ? hy * hx : 0.f;
    const float w01 = (vy0 && vx1) ? hy * lx : 0.f;
    const float w10 = (vy1 && vx0) ? ly * hx : 0.f;
    const float w11 = (vy1 && vx1) ? ly * lx : 0.f;
    const int cy0 = min(max(y0, 0), Hh - 1), cy1 = min(max(y1, 0), Hh - 1);
    const int cx0 = min(max(x0, 0), Ww - 1), cx1 = min(max(x1, 0), Ww - 1);
    const int i00 = cy0 * Ww + cx0, i01 = cy0 * Ww + cx1;
    const int i10 = cy1 * Ww + cx0, i11 = cy1 * Ww + cx1;
    const float* base = (g < 8) ? (fp  + (size_t)(b * 64 + g * 8) * HW)
                                : (fn2 + (size_t)(b * 64 + (g - 8) * 8) * HW);
    float* smp = sm + pix * 1152 + (g * 8) * 9 + k;
#pragma unroll
    for (int c = 0; c < 8; ++c) {
      const float* cb = base + (size_t)c * HW;
      const float v = w00 * cb[i00] + w01 * cb[i01] + w10 * cb[i10] + w11 * cb[i11];
      smp[c * 9] = m * v;
    }
  }
  __syncthreads();

  const int pix = tid >> 6;
  const int co  = tid & 63;
  float acc = dc_bias[co];
  const float* smp = sm + pix * 1152;
#pragma unroll 4
  for (int j = 0; j < 1152; j += 4) {
    const float4 s = *(const float4*)(smp + j);
    acc = fmaf(s.x, wT[(j + 0) * 64 + co], acc);
    acc = fmaf(s.y, wT[(j + 1) * 64 + co], acc);
    acc = fmaf(s.z, wT[(j + 2) * 64 + co], acc);
    acc = fmaf(s.w, wT[(j + 3) * 64 + co], acc);
  }
  out[(size_t)(b * 64 + co) * HW + h * Ww + w0 + pix] = acc;
}

extern "C" void kernel_launch(void* const* d_in, const int* in_sizes, int n_in,
                              void* d_out, int out_size, void* d_ws, size_t ws_size,
                              hipStream_t stream) {
  const float* extra = (const float*)d_in[0];
  const float* f1    = (const float*)d_in[1];
  const float* f2    = (const float*)d_in[2];
  const float* fp    = (const float*)d_in[3];
  const float* fn2   = (const float*)d_in[4];
  const float* w_off = (const float*)d_in[5];
  const float* b_off = (const float*)d_in[6];
  const float* dcw   = (const float*)d_in[7];
  const float* dcb   = (const float*)d_in[8];
  float* out = (float*)d_out;

  float* ws       = (float*)d_ws;
  float* wT       = ws;                       // 73728 floats
  float* off_buf  = ws + 73728;               // 2*288*HW = 9437184 floats
  float* mask_buf = off_buf + 2 * 288 * HW;   // 2*144*HW = 4718592 floats
  // total ~56.9 MB of d_ws

  hipLaunchKernelGGL(k_transpose_w, dim3(288), dim3(256), 0, stream, dcw, wT);
  hipLaunchKernelGGL(k_offconv, dim3(2, 128, 36), dim3(256), 0, stream,
                     extra, f1, f2, w_off, b_off, off_buf, mask_buf);
  hipLaunchKernelGGL(k_deform, dim3(32, 128, 2), dim3(256), 0, stream,
                     fp, fn2, off_buf, mask_buf, wT, dcb, out);
}

// Round 3
// 936.798 us; speedup vs baseline: 2.2576x; 2.2576x over previous
//
#include <hip/hip_runtime.h>
#include <math.h>

#define Hh 128
#define Ww 128
#define HW (128*128)
#define CIN_OFF 196
#define COFF 432

typedef _Float16 half8 __attribute__((ext_vector_type(8)));
typedef _Float16 half2v __attribute__((ext_vector_type(2)));
typedef float f32x4 __attribute__((ext_vector_type(4)));

// ---------------- kernel 0a: transpose dc_weight [64][128][9] -> wT[j=ci*9+k][64] ----------
__global__ __launch_bounds__(256) void k_transpose_w(const float* __restrict__ dcw,
                                                     float* __restrict__ wT) {
  int idx = blockIdx.x * 256 + threadIdx.x;
  if (idx < 64 * 1152) {
    int co = idx / 1152;
    int j  = idx - co * 1152;
    wT[j * 64 + co] = dcw[idx];
  }
}

// ---------------- kernel 0b: w_off [432][196][9] fp32 -> Bp[448][9*224] fp16 --------------
// Bp[n][t*224+ci] = w_off[n][ci][t]; zero-padded for n>=432, ci>=196.
__global__ __launch_bounds__(256) void k_prep_w(const float* __restrict__ w_off,
                                                _Float16* __restrict__ Bp) {
  int idx = blockIdx.x * 256 + threadIdx.x;   // 448*2016 = 903168
  if (idx >= 448 * 2016) return;
  int n = idx / 2016;
  int k = idx - n * 2016;
  int t = k / 224;
  int ci = k - t * 224;
  float v = 0.f;
  if (n < COFF && ci < CIN_OFF) v = w_off[((size_t)n * CIN_OFF + ci) * 9 + t];
  Bp[idx] = (_Float16)v;
}

// ---------------- kernel 1: offset conv as fp16 MFMA implicit GEMM ------------------------
// grid (128 h, 2 b), block 512 (8 waves: 2 M-waves x 4 N-waves).
// M = 128 pixels (one row), N = 448 (432 real), K = 9 taps x 224 ci (196 real).
__global__ __launch_bounds__(512) void k_offconv_mfma(
    const float* __restrict__ extra, const float* __restrict__ f1, const float* __restrict__ f2,
    const _Float16* __restrict__ Bp, const float* __restrict__ b_off,
    float* __restrict__ off_buf, float* __restrict__ mask_buf) {
  __shared__ __align__(16) _Float16 xs[3][132][40];  // [row][px(+1 shift)][ci chunk pad 40]
  const int h    = blockIdx.x;
  const int b    = blockIdx.y;
  const int tid  = (int)threadIdx.x;
  const int lane = tid & 63;
  const int wid  = tid >> 6;
  const int wm   = wid >> 2;      // 0..1
  const int wn   = wid & 3;       // 0..3
  const int m_base = wm * 64;
  const int n_base = wn * 112;
  const int l15 = lane & 15;
  const int l4  = lane >> 4;

  f32x4 acc[4][7];
#pragma unroll
  for (int i = 0; i < 4; ++i)
#pragma unroll
    for (int j = 0; j < 7; ++j) acc[i][j] = (f32x4){0.f, 0.f, 0.f, 0.f};

  // zero the p=0 and p=129 edge columns ONCE (image cols -1 and 128).
  // Staging never writes p=0/129, so this persists across chunks.
  // (Round-2 bug: `rem & 39` is not mod-40 -> xs[r][edge][8..31] stayed
  //  uninitialized -> NaN through MFMA. Fixed with explicit select.)
  if (tid < 240) {
    const int r   = tid / 80;
    const int rem = tid - r * 80;
    const int p   = (rem >= 40) ? 129 : 0;
    const int ci  = (rem >= 40) ? (rem - 40) : rem;
    xs[r][p][ci] = (_Float16)0.f;
  }

#pragma unroll 1
  for (int chunk = 0; chunk < 7; ++chunk) {
    const int ci0 = chunk * 32;
    __syncthreads();
    // stage 32 ci x 3 rows x 128 px, fp32 -> fp16, transposed to [row][px][ci]
#pragma unroll
    for (int it = 0; it < 3; ++it) {
      const int tt = tid + it * 512;       // 0..1535
      const int p2 = tt & 15;              // ci pair index
      const int r  = (tt >> 4) % 3;
      const int q  = tt / 48;              // 0..31 (4-px quad)
      const int gh = h - 1 + r;
      const int ci_a = ci0 + 2 * p2;
      float4 va = {0.f, 0.f, 0.f, 0.f}, vb = va;
      if ((unsigned)gh < (unsigned)Hh) {
        if (ci_a < CIN_OFF) {
          const float* xp = (ci_a < 192) ? extra + (size_t)(b * 192 + ci_a) * HW
                          : (ci_a < 194) ? f1 + (size_t)(b * 2 + (ci_a - 192)) * HW
                                         : f2 + (size_t)(b * 2 + (ci_a - 194)) * HW;
          va = *(const float4*)(xp + gh * Ww + 4 * q);
        }
        if (ci_a + 1 < CIN_OFF) {
          const int cb = ci_a + 1;
          const float* xp = (cb < 192) ? extra + (size_t)(b * 192 + cb) * HW
                          : (cb < 194) ? f1 + (size_t)(b * 2 + (cb - 192)) * HW
                                       : f2 + (size_t)(b * 2 + (cb - 194)) * HW;
          vb = *(const float4*)(xp + gh * Ww + 4 * q);
        }
      }
      const float av[4] = {va.x, va.y, va.z, va.w};
      const float bv[4] = {vb.x, vb.y, vb.z, vb.w};
#pragma unroll
      for (int i = 0; i < 4; ++i) {
        half2v pk;
        pk[0] = (_Float16)av[i];
        pk[1] = (_Float16)bv[i];
        *reinterpret_cast<half2v*>(&xs[r][1 + 4 * q + i][2 * p2]) = pk;
      }
    }
    __syncthreads();

#pragma unroll 1
    for (int t = 0; t < 9; ++t) {
      const int ki = (t >= 6) ? 2 : (t >= 3 ? 1 : 0);
      const int kj = t - 3 * ki;
      half8 bf[7];
      const size_t kcol = (size_t)(t * 224 + ci0 + l4 * 8);
#pragma unroll
      for (int f = 0; f < 7; ++f)
        bf[f] = *(const half8*)(Bp + (size_t)(n_base + f * 16 + l15) * 2016 + kcol);
      half8 af[4];
#pragma unroll
      for (int mf = 0; mf < 4; ++mf)
        af[mf] = *reinterpret_cast<const half8*>(&xs[ki][m_base + mf * 16 + l15 + kj][l4 * 8]);
#pragma unroll
      for (int mf = 0; mf < 4; ++mf)
#pragma unroll
        for (int f = 0; f < 7; ++f)
          acc[mf][f] = __builtin_amdgcn_mfma_f32_16x16x32_f16(af[mf], bf[f], acc[mf][f], 0, 0, 0);
    }
  }

  // epilogue: bias + 10*tanh + flow-add (co<288) / sigmoid (co>=288)
  const int hw0 = h * Ww;
#pragma unroll
  for (int f = 0; f < 7; ++f) {
    const int n = n_base + f * 16 + l15;
    if (n >= COFF) continue;
    const float bias = b_off[n];
    const bool isOff = (n < 288);
    const float* fl = (n < 144) ? f1 : f2;
    const size_t fladd = (size_t)(b * 2 + ((n & 1) ^ 1)) * HW;
#pragma unroll
    for (int mf = 0; mf < 4; ++mf) {
#pragma unroll
      for (int r = 0; r < 4; ++r) {
        const int m = m_base + mf * 16 + l4 * 4 + r;
        const float v = acc[mf][f][r] + bias;
        const int p = hw0 + m;
        if (isOff) {
          off_buf[(size_t)(b * 288 + n) * HW + p] = 10.f * tanhf(v) + fl[fladd + p];
        } else {
          mask_buf[(size_t)(b * 144 + (n - 288)) * HW + p] = 1.f / (1.f + expf(-v));
        }
      }
    }
  }
}

// ---------------- kernel 2: modulated deformable conv (unchanged) ------------------------
__global__ __launch_bounds__(256) void k_deform(
    const float* __restrict__ fp, const float* __restrict__ fn2,
    const float* __restrict__ off_buf, const float* __restrict__ mask_buf,
    const float* __restrict__ wT, const float* __restrict__ dc_bias,
    float* __restrict__ out) {
  __shared__ float sm[4 * 1152];
  const int w0  = blockIdx.x * 4;
  const int h   = blockIdx.y;
  const int b   = blockIdx.z;
  const int tid = (int)threadIdx.x;

  for (int p = tid; p < 576; p += 256) {
    const int pix = p / 144;
    const int r   = p - pix * 144;
    const int g   = r / 9;
    const int k   = r - g * 9;
    const int w   = w0 + pix;
    const int hw  = h * Ww + w;
    const float oy = off_buf[(size_t)(b * 288 + g * 18 + k * 2 + 0) * HW + hw];
    const float ox = off_buf[(size_t)(b * 288 + g * 18 + k * 2 + 1) * HW + hw];
    const float m  = mask_buf[(size_t)(b * 144 + g * 9 + k) * HW + hw];
    const int ki = k / 3, kj = k - (k / 3) * 3;
    const float py = (float)(h - 1 + ki) + oy;
    const float px = (float)(w - 1 + kj) + ox;
    const float y0f = floorf(py), x0f = floorf(px);
    const int y0 = (int)y0f, x0 = (int)x0f;
    const float ly = py - y0f, lx = px - x0f;
    const float hy = 1.f - ly, hx = 1.f - lx;
    const int y1 = y0 + 1, x1 = x0 + 1;
    const bool vy0 = (unsigned)y0 < (unsigned)Hh, vy1 = (unsigned)y1 < (unsigned)Hh;
    const bool vx0 = (unsigned)x0 < (unsigned)Ww, vx1 = (unsigned)x1 < (unsigned)Ww;
    const float w00 = (vy0 && vx0) ? hy * hx : 0.f;
    const float w01 = (vy0 && vx1) ? hy * lx : 0.f;
    const float w10 = (vy1 && vx0) ? ly * hx : 0.f;
    const float w11 = (vy1 && vx1) ? ly * lx : 0.f;
    const int cy0 = min(max(y0, 0), Hh - 1), cy1 = min(max(y1, 0), Hh - 1);
    const int cx0 = min(max(x0, 0), Ww - 1), cx1 = min(max(x1, 0), Ww - 1);
    const int i00 = cy0 * Ww + cx0, i01 = cy0 * Ww + cx1;
    const int i10 = cy1 * Ww + cx0, i11 = cy1 * Ww + cx1;
    const float* base = (g < 8) ? (fp  + (size_t)(b * 64 + g * 8) * HW)
                                : (fn2 + (size_t)(b * 64 + (g - 8) * 8) * HW);
    float* smp = sm + pix * 1152 + (g * 8) * 9 + k;
#pragma unroll
    for (int c = 0; c < 8; ++c) {
      const float* cb = base + (size_t)c * HW;
      const float v = w00 * cb[i00] + w01 * cb[i01] + w10 * cb[i10] + w11 * cb[i11];
      smp[c * 9] = m * v;
    }
  }
  __syncthreads();

  const int pix = tid >> 6;
  const int co  = tid & 63;
  float acc = dc_bias[co];
  const float* smp = sm + pix * 1152;
#pragma unroll 4
  for (int j = 0; j < 1152; j += 4) {
    const float4 s = *(const float4*)(smp + j);
    acc = fmaf(s.x, wT[(j + 0) * 64 + co], acc);
    acc = fmaf(s.y, wT[(j + 1) * 64 + co], acc);
    acc = fmaf(s.z, wT[(j + 2) * 64 + co], acc);
    acc = fmaf(s.w, wT[(j + 3) * 64 + co], acc);
  }
  out[(size_t)(b * 64 + co) * HW + h * Ww + w0 + pix] = acc;
}

extern "C" void kernel_launch(void* const* d_in, const int* in_sizes, int n_in,
                              void* d_out, int out_size, void* d_ws, size_t ws_size,
                              hipStream_t stream) {
  const float* extra = (const float*)d_in[0];
  const float* f1    = (const float*)d_in[1];
  const float* f2    = (const float*)d_in[2];
  const float* fp    = (const float*)d_in[3];
  const float* fn2   = (const float*)d_in[4];
  const float* w_off = (const float*)d_in[5];
  const float* b_off = (const float*)d_in[6];
  const float* dcw   = (const float*)d_in[7];
  const float* dcb   = (const float*)d_in[8];
  float* out = (float*)d_out;

  float* ws       = (float*)d_ws;
  float* wT       = ws;                       // 73728 floats
  float* off_buf  = ws + 73728;               // 2*288*HW floats
  float* mask_buf = off_buf + 2 * 288 * HW;   // 2*144*HW floats
  _Float16* Bp    = (_Float16*)(mask_buf + 2 * 144 * HW);  // 448*2016 halves (~1.8 MB)

  hipLaunchKernelGGL(k_transpose_w, dim3(288), dim3(256), 0, stream, dcw, wT);
  hipLaunchKernelGGL(k_prep_w, dim3((448 * 2016 + 255) / 256), dim3(256), 0, stream, w_off, Bp);
  hipLaunchKernelGGL(k_offconv_mfma, dim3(128, 2), dim3(512), 0, stream,
                     extra, f1, f2, Bp, b_off, off_buf, mask_buf);
  hipLaunchKernelGGL(k_deform, dim3(32, 128, 2), dim3(256), 0, stream,
                     fp, fn2, off_buf, mask_buf, wT, dcb, out);
}

// Round 4
// 227.911 us; speedup vs baseline: 9.2797x; 4.1104x over previous
//
#include <hip/hip_runtime.h>
#include <math.h>

#define Hh 128
#define Ww 128
#define HW (128*128)
#define CIN_OFF 196
#define COFF 432

typedef _Float16 half8 __attribute__((ext_vector_type(8)));
typedef _Float16 half2v __attribute__((ext_vector_type(2)));
typedef float f32x4 __attribute__((ext_vector_type(4)));

static __device__ __forceinline__ half8 splat8(float v) {
  _Float16 h = (_Float16)v;
  half8 r = {h, h, h, h, h, h, h, h};
  return r;
}

// ---------------- kernel 0a: dc_weight [64][128][9] fp32 -> wH[co][k*128+ci] fp16 --------
__global__ __launch_bounds__(256) void k_prep_dcw(const float* __restrict__ dcw,
                                                  _Float16* __restrict__ wH) {
  int idx = blockIdx.x * 256 + threadIdx.x;   // 64*1152 = 73728
  if (idx < 64 * 1152) {
    int co = idx / 1152;
    int j  = idx - co * 1152;
    int k  = j >> 7;
    int ci = j & 127;
    wH[idx] = (_Float16)dcw[(co * 128 + ci) * 9 + k];
  }
}

// ---------------- kernel 0b: w_off [432][196][9] fp32 -> Bp[448][9*224] fp16 --------------
__global__ __launch_bounds__(256) void k_prep_w(const float* __restrict__ w_off,
                                                _Float16* __restrict__ Bp) {
  int idx = blockIdx.x * 256 + threadIdx.x;   // 448*2016 = 903168
  if (idx >= 448 * 2016) return;
  int n = idx / 2016;
  int k = idx - n * 2016;
  int t = k / 224;
  int ci = k - t * 224;
  float v = 0.f;
  if (n < COFF && ci < CIN_OFF) v = w_off[((size_t)n * CIN_OFF + ci) * 9 + t];
  Bp[idx] = (_Float16)v;
}

// ---------------- kernel 0c: features -> channel-last fp16 featT[b][hw][128] --------------
// ch 0..63 = feat_prop, 64..127 = feat_n2. Reads lane-coalesced; writes 16B/lane.
__global__ __launch_bounds__(256) void k_prep_feat(const float* __restrict__ fp,
                                                   const float* __restrict__ fn2,
                                                   _Float16* __restrict__ featT) {
  const int t = blockIdx.x * 256 + threadIdx.x;   // 0..32767 = b*HW+hw
  const int b = t >> 14;
  const int hw = t & 16383;
#pragma unroll
  for (int c8 = 0; c8 < 16; ++c8) {
    const float* src = (c8 < 8) ? fp : fn2;
    const int ch0 = (c8 & 7) * 8;
    half8 v;
#pragma unroll
    for (int c = 0; c < 8; ++c)
      v[c] = (_Float16)src[(size_t)(b * 64 + ch0 + c) * HW + hw];
    *(half8*)(featT + (size_t)t * 128 + c8 * 8) = v;
  }
}

// ---------------- kernel 1: offset conv as fp16 MFMA implicit GEMM ------------------------
// grid (128 h, 2 b), block 512 (8 waves: 2 M x 4 N). Outputs pixel-major off/mask.
__global__ __launch_bounds__(512) void k_offconv_mfma(
    const float* __restrict__ extra, const float* __restrict__ f1, const float* __restrict__ f2,
    const _Float16* __restrict__ Bp, const float* __restrict__ b_off,
    float* __restrict__ off_pm, _Float16* __restrict__ mask_pm) {
  __shared__ __align__(16) _Float16 xs[3][132][40];  // [row][px(+1 shift)][ci chunk pad 40]
  const int h    = blockIdx.x;
  const int b    = blockIdx.y;
  const int tid  = (int)threadIdx.x;
  const int lane = tid & 63;
  const int wid  = tid >> 6;
  const int wm   = wid >> 2;      // 0..1
  const int wn   = wid & 3;       // 0..3
  const int m_base = wm * 64;
  const int n_base = wn * 112;
  const int l15 = lane & 15;
  const int l4  = lane >> 4;

  f32x4 acc[4][7];
#pragma unroll
  for (int i = 0; i < 4; ++i)
#pragma unroll
    for (int j = 0; j < 7; ++j) acc[i][j] = (f32x4){0.f, 0.f, 0.f, 0.f};

  // zero the p=0 and p=129 edge columns ONCE (image cols -1 and 128)
  if (tid < 240) {
    const int r   = tid / 80;
    const int rem = tid - r * 80;
    const int p   = (rem >= 40) ? 129 : 0;
    const int ci  = (rem >= 40) ? (rem - 40) : rem;
    xs[r][p][ci] = (_Float16)0.f;
  }

#pragma unroll 1
  for (int chunk = 0; chunk < 7; ++chunk) {
    const int ci0 = chunk * 32;
    __syncthreads();
#pragma unroll
    for (int it = 0; it < 3; ++it) {
      const int tt = tid + it * 512;       // 0..1535
      const int p2 = tt & 15;              // ci pair index
      const int r  = (tt >> 4) % 3;
      const int q  = tt / 48;              // 0..31 (4-px quad)
      const int gh = h - 1 + r;
      const int ci_a = ci0 + 2 * p2;
      float4 va = {0.f, 0.f, 0.f, 0.f}, vb = va;
      if ((unsigned)gh < (unsigned)Hh) {
        if (ci_a < CIN_OFF) {
          const float* xp = (ci_a < 192) ? extra + (size_t)(b * 192 + ci_a) * HW
                          : (ci_a < 194) ? f1 + (size_t)(b * 2 + (ci_a - 192)) * HW
                                         : f2 + (size_t)(b * 2 + (ci_a - 194)) * HW;
          va = *(const float4*)(xp + gh * Ww + 4 * q);
        }
        if (ci_a + 1 < CIN_OFF) {
          const int cb = ci_a + 1;
          const float* xp = (cb < 192) ? extra + (size_t)(b * 192 + cb) * HW
                          : (cb < 194) ? f1 + (size_t)(b * 2 + (cb - 192)) * HW
                                       : f2 + (size_t)(b * 2 + (cb - 194)) * HW;
          vb = *(const float4*)(xp + gh * Ww + 4 * q);
        }
      }
      const float av[4] = {va.x, va.y, va.z, va.w};
      const float bv[4] = {vb.x, vb.y, vb.z, vb.w};
#pragma unroll
      for (int i = 0; i < 4; ++i) {
        half2v pk;
        pk[0] = (_Float16)av[i];
        pk[1] = (_Float16)bv[i];
        *reinterpret_cast<half2v*>(&xs[r][1 + 4 * q + i][2 * p2]) = pk;
      }
    }
    __syncthreads();

#pragma unroll 1
    for (int t = 0; t < 9; ++t) {
      const int ki = (t >= 6) ? 2 : (t >= 3 ? 1 : 0);
      const int kj = t - 3 * ki;
      half8 bf[7];
      const size_t kcol = (size_t)(t * 224 + ci0 + l4 * 8);
#pragma unroll
      for (int f = 0; f < 7; ++f)
        bf[f] = *(const half8*)(Bp + (size_t)(n_base + f * 16 + l15) * 2016 + kcol);
      half8 af[4];
#pragma unroll
      for (int mf = 0; mf < 4; ++mf)
        af[mf] = *reinterpret_cast<const half8*>(&xs[ki][m_base + mf * 16 + l15 + kj][l4 * 8]);
#pragma unroll
      for (int mf = 0; mf < 4; ++mf)
#pragma unroll
        for (int f = 0; f < 7; ++f)
          acc[mf][f] = __builtin_amdgcn_mfma_f32_16x16x32_f16(af[mf], bf[f], acc[mf][f], 0, 0, 0);
    }
  }

  // epilogue: bias + 10*tanh + flow-add -> off_pm[b][hw][288]; sigmoid -> mask_pm[b][hw][144]
  const int hw0 = h * Ww;
#pragma unroll
  for (int f = 0; f < 7; ++f) {
    const int n = n_base + f * 16 + l15;
    if (n >= COFF) continue;
    const float bias = b_off[n];
    const bool isOff = (n < 288);
    const float* fl = (n < 144) ? f1 : f2;
    const size_t fladd = (size_t)(b * 2 + ((n & 1) ^ 1)) * HW;
#pragma unroll
    for (int mf = 0; mf < 4; ++mf) {
#pragma unroll
      for (int rr = 0; rr < 4; ++rr) {
        const int m = m_base + mf * 16 + l4 * 4 + rr;
        const float v = acc[mf][f][rr] + bias;
        const int p = hw0 + m;
        if (isOff) {
          off_pm[((size_t)b * HW + p) * 288 + n] = 10.f * tanhf(v) + fl[fladd + p];
        } else {
          mask_pm[((size_t)b * HW + p) * 144 + (n - 288)] = (_Float16)(1.f / (1.f + expf(-v)));
        }
      }
    }
  }
}

// ---------------- kernel 2: modulated deformable conv, 16 px/block, MFMA phase 2 ----------
// grid (8, 128, 2), block 256 (4 waves).
// phase 1: 16px x 144 (g,k) samples -> fp16 LDS A[16][1152] (mask folded, XOR-swizzled)
// phase 2: C[16][64] = A[16][1152] x wH[64][1152]^T via mfma 16x16x32, K split over 4 waves
__global__ __launch_bounds__(256) void k_deform2(
    const _Float16* __restrict__ featT, const float* __restrict__ off_pm,
    const _Float16* __restrict__ mask_pm, const _Float16* __restrict__ wH,
    const float* __restrict__ dcb, float* __restrict__ out) {
  __shared__ __align__(16) char smem[16 * 1160 * 2];   // 37120 B
  _Float16* sm = (_Float16*)smem;                      // sm[pix][1160], j = k*128 + g^swz*8 + c
  float* red = (float*)smem;                           // red[w][16][66] (aliased after sync)
  const int w0  = blockIdx.x * 16;
  const int h   = blockIdx.y;
  const int b   = blockIdx.z;
  const int tid = (int)threadIdx.x;
  const int lane = tid & 63, wid = tid >> 6;
  const int l15 = lane & 15, l4 = lane >> 4;

  // ---- phase 1: gather + bilinear + mask -> LDS ----
#pragma unroll 1
  for (int i = 0; i < 9; ++i) {
    const int p   = tid + i * 256;        // 0..2303
    const int pix = p / 144;
    const int r   = p - pix * 144;
    const int g   = r / 9;
    const int k   = r - g * 9;
    const int w   = w0 + pix;
    const int hw  = h * Ww + w;
    const float2 off = *(const float2*)(off_pm + ((size_t)b * HW + hw) * 288 + 2 * r);
    const float mk = (float)mask_pm[((size_t)b * HW + hw) * 144 + r];
    const int ki = (k >= 6) ? 2 : (k >= 3 ? 1 : 0);
    const int kj = k - 3 * ki;
    const float py = (float)(h - 1 + ki) + off.x;
    const float px = (float)(w - 1 + kj) + off.y;
    const float y0f = floorf(py), x0f = floorf(px);
    const int y0 = (int)y0f, x0 = (int)x0f;
    const float ly = py - y0f, lx = px - x0f;
    const float hy = 1.f - ly, hx = 1.f - lx;
    const int y1 = y0 + 1, x1 = x0 + 1;
    const bool vy0 = (unsigned)y0 < (unsigned)Hh, vy1 = (unsigned)y1 < (unsigned)Hh;
    const bool vx0 = (unsigned)x0 < (unsigned)Ww, vx1 = (unsigned)x1 < (unsigned)Ww;
    const float w00 = (vy0 && vx0) ? hy * hx : 0.f;
    const float w01 = (vy0 && vx1) ? hy * lx : 0.f;
    const float w10 = (vy1 && vx0) ? ly * hx : 0.f;
    const float w11 = (vy1 && vx1) ? ly * lx : 0.f;
    const int cy0 = min(max(y0, 0), Hh - 1), cy1 = min(max(y1, 0), Hh - 1);
    const int cx0 = min(max(x0, 0), Ww - 1), cx1 = min(max(x1, 0), Ww - 1);
    const size_t bb = (size_t)b * HW;
    const int gc = g * 8;
    const half8 s00 = *(const half8*)(featT + ((bb + cy0 * Ww + cx0) << 7) + gc);
    const half8 s01 = *(const half8*)(featT + ((bb + cy0 * Ww + cx1) << 7) + gc);
    const half8 s10 = *(const half8*)(featT + ((bb + cy1 * Ww + cx0) << 7) + gc);
    const half8 s11 = *(const half8*)(featT + ((bb + cy1 * Ww + cx1) << 7) + gc);
    half8 v = s00 * splat8(w00) + s01 * splat8(w01) + s10 * splat8(w10) + s11 * splat8(w11);
    v = v * splat8(mk);
    const int swz = (g ^ (k & 7)) << 3;
    *(half8*)(sm + pix * 1160 + k * 128 + swz) = v;
  }
  __syncthreads();

  // ---- phase 2: MFMA, K-split over 4 waves (9 steps of K=32 each) ----
  f32x4 acc[4];
#pragma unroll
  for (int nf = 0; nf < 4; ++nf) acc[nf] = (f32x4){0.f, 0.f, 0.f, 0.f};
#pragma unroll
  for (int j = 0; j < 9; ++j) {
    const int s  = wid * 9 + j;           // global K-step 0..35
    const int k  = s >> 2;                // tap
    const int cg = s & 3;                 // 32-chunk within tap
    const int gidx = cg * 4 + l4;         // logical group of this lane's 8 ci
    const half8 af = *(const half8*)(sm + l15 * 1160 + k * 128 + ((gidx ^ (k & 7)) << 3));
    const int koff = s * 32 + l4 * 8;
#pragma unroll
    for (int nf = 0; nf < 4; ++nf) {
      const half8 bf = *(const half8*)(wH + (nf * 16 + l15) * 1152 + koff);
      acc[nf] = __builtin_amdgcn_mfma_f32_16x16x32_f16(af, bf, acc[nf], 0, 0, 0);
    }
  }
  __syncthreads();   // done reading sm; alias as red
#pragma unroll
  for (int nf = 0; nf < 4; ++nf)
#pragma unroll
    for (int rr = 0; rr < 4; ++rr)
      red[(wid * 16 + l4 * 4 + rr) * 66 + nf * 16 + l15] = acc[nf][rr];
  __syncthreads();

  // ---- reduce 4 partials + bias, coalesced store ----
  const int m  = tid & 15;
  const int ng = tid >> 4;                // 0..15
#pragma unroll
  for (int i = 0; i < 4; ++i) {
    const int n = ng + 16 * i;
    float val = red[(0 * 16 + m) * 66 + n] + red[(1 * 16 + m) * 66 + n] +
                red[(2 * 16 + m) * 66 + n] + red[(3 * 16 + m) * 66 + n];
    out[(size_t)(b * 64 + n) * HW + h * Ww + w0 + m] = val + dcb[n];
  }
}

extern "C" void kernel_launch(void* const* d_in, const int* in_sizes, int n_in,
                              void* d_out, int out_size, void* d_ws, size_t ws_size,
                              hipStream_t stream) {
  const float* extra = (const float*)d_in[0];
  const float* f1    = (const float*)d_in[1];
  const float* f2    = (const float*)d_in[2];
  const float* fp    = (const float*)d_in[3];
  const float* fn2   = (const float*)d_in[4];
  const float* w_off = (const float*)d_in[5];
  const float* b_off = (const float*)d_in[6];
  const float* dcw   = (const float*)d_in[7];
  const float* dcb   = (const float*)d_in[8];
  float* out = (float*)d_out;

  // ws layout (~57.5 MB)
  float*    off_pm  = (float*)d_ws;                      // 2*HW*288 f32 = 37.7 MB
  _Float16* mask_pm = (_Float16*)(off_pm + 2 * 288 * HW);// 2*HW*144 fp16 = 9.4 MB
  _Float16* featT   = mask_pm + 2 * 144 * HW;            // 2*HW*128 fp16 = 8.4 MB
  _Float16* Bp      = featT + 2 * 128 * HW;              // 448*2016 fp16 = 1.8 MB
  _Float16* wH      = Bp + 448 * 2016;                   // 64*1152 fp16 = 0.15 MB

  hipLaunchKernelGGL(k_prep_dcw, dim3(288), dim3(256), 0, stream, dcw, wH);
  hipLaunchKernelGGL(k_prep_w, dim3((448 * 2016 + 255) / 256), dim3(256), 0, stream, w_off, Bp);
  hipLaunchKernelGGL(k_prep_feat, dim3(128), dim3(256), 0, stream, fp, fn2, featT);
  hipLaunchKernelGGL(k_offconv_mfma, dim3(128, 2), dim3(512), 0, stream,
                     extra, f1, f2, Bp, b_off, off_pm, mask_pm);
  hipLaunchKernelGGL(k_deform2, dim3(8, 128, 2), dim3(256), 0, stream,
                     featT, off_pm, mask_pm, wH, dcb, out);
}

// Round 5
// 213.541 us; speedup vs baseline: 9.9041x; 1.0673x over previous
//
#include <hip/hip_runtime.h>
#include <math.h>

#define Hh 128
#define Ww 128
#define HW (128*128)
#define CIN_OFF 196
#define COFF 432

typedef _Float16 half8 __attribute__((ext_vector_type(8)));
typedef _Float16 half2v __attribute__((ext_vector_type(2)));
typedef float f32x4 __attribute__((ext_vector_type(4)));

static __device__ __forceinline__ half8 splat8(float v) {
  _Float16 h = (_Float16)v;
  half8 r = {h, h, h, h, h, h, h, h};
  return r;
}

// ---------------- kernel 0a: dc_weight [64][128][9] fp32 -> wH[co][k*128+ci] fp16 --------
__global__ __launch_bounds__(256) void k_prep_dcw(const float* __restrict__ dcw,
                                                  _Float16* __restrict__ wH) {
  int idx = blockIdx.x * 256 + threadIdx.x;   // 64*1152 = 73728
  if (idx < 64 * 1152) {
    int co = idx / 1152;
    int j  = idx - co * 1152;
    int k  = j >> 7;
    int ci = j & 127;
    wH[idx] = (_Float16)dcw[(co * 128 + ci) * 9 + k];
  }
}

// ---------------- kernel 0b: w_off [432][196][9] fp32 -> Bp[448][9*224] fp16 --------------
__global__ __launch_bounds__(256) void k_prep_w(const float* __restrict__ w_off,
                                                _Float16* __restrict__ Bp) {
  int idx = blockIdx.x * 256 + threadIdx.x;   // 448*2016 = 903168
  if (idx >= 448 * 2016) return;
  int n = idx / 2016;
  int k = idx - n * 2016;
  int t = k / 224;
  int ci = k - t * 224;
  float v = 0.f;
  if (n < COFF && ci < CIN_OFF) v = w_off[((size_t)n * CIN_OFF + ci) * 9 + t];
  Bp[idx] = (_Float16)v;
}

// ---------------- kernel 0c: features -> per-group channel-last fp16 ---------------------
// featT[b][g][hw][8c], g 0..15 (g<8 = feat_prop, g>=8 = feat_n2).
// A sample's 4 bilinear corners are 16B records; x-adjacent corners share a line.
__global__ __launch_bounds__(256) void k_prep_feat(const float* __restrict__ fp,
                                                   const float* __restrict__ fn2,
                                                   _Float16* __restrict__ featT) {
  const int t = blockIdx.x * 256 + threadIdx.x;   // 0..32767 = b*HW+hw
  const int b = t >> 14;
  const int hw = t & 16383;
#pragma unroll
  for (int g = 0; g < 16; ++g) {
    const float* src = (g < 8) ? fp : fn2;
    const int ch0 = (g & 7) * 8;
    half8 v;
#pragma unroll
    for (int c = 0; c < 8; ++c)
      v[c] = (_Float16)src[(size_t)(b * 64 + ch0 + c) * HW + hw];
    *(half8*)(featT + (((size_t)(b * 16 + g)) * HW + hw) * 8) = v;
  }
}

// ---------------- kernel 1: offset conv as fp16 MFMA implicit GEMM ------------------------
// grid (128 h, 2 b, 2 nsplit), block 256 (4 waves: 2M x 2N).
// M = 128 px (one row), N = 224 per split, K = 9 taps x 224 ci.
// Double-buffered LDS + register prefetch of next chunk; 1 sync per chunk.
__global__ __launch_bounds__(256, 2) void k_offconv_mfma(
    const float* __restrict__ extra, const float* __restrict__ f1, const float* __restrict__ f2,
    const _Float16* __restrict__ Bp, const float* __restrict__ b_off,
    float* __restrict__ off_pm, _Float16* __restrict__ mask_pm) {
  __shared__ __align__(16) _Float16 xs[2][3][132][40];  // 2 x [row][px(+1)][ci pad 40]
  const int h    = blockIdx.x;
  const int b    = blockIdx.y;
  const int ns   = blockIdx.z;
  const int tid  = (int)threadIdx.x;
  const int lane = tid & 63;
  const int wid  = tid >> 6;      // 0..3
  const int wm   = wid >> 1;      // 0..1
  const int wn   = wid & 1;       // 0..1
  const int m_base = wm * 64;
  const int n_base = ns * 224 + wn * 112;
  const int l15 = lane & 15;
  const int l4  = lane >> 4;

  f32x4 acc[4][7];
#pragma unroll
  for (int i = 0; i < 4; ++i)
#pragma unroll
    for (int j = 0; j < 7; ++j) acc[i][j] = (f32x4){0.f, 0.f, 0.f, 0.f};

  float4 ra[6][2];   // prefetch registers: 6 (it) x (even ci, odd ci)

  auto stage_load = [&](int chunkv) {
    const int ci0 = chunkv * 32;
#pragma unroll
    for (int it = 0; it < 6; ++it) {
      const int tt = tid + it * 256;       // 0..1535
      const int p2 = tt & 15;              // ci pair index
      const int r  = (tt >> 4) % 3;
      const int q  = tt / 48;              // 0..31 (4-px quad)
      const int gh = h - 1 + r;
      const int ci_a = ci0 + 2 * p2;
      float4 va = {0.f, 0.f, 0.f, 0.f}, vb = va;
      if ((unsigned)gh < (unsigned)Hh) {
        if (ci_a < CIN_OFF) {
          const float* xp = (ci_a < 192) ? extra + (size_t)(b * 192 + ci_a) * HW
                          : (ci_a < 194) ? f1 + (size_t)(b * 2 + (ci_a - 192)) * HW
                                         : f2 + (size_t)(b * 2 + (ci_a - 194)) * HW;
          va = *(const float4*)(xp + gh * Ww + 4 * q);
        }
        if (ci_a + 1 < CIN_OFF) {
          const int cb = ci_a + 1;
          const float* xp = (cb < 192) ? extra + (size_t)(b * 192 + cb) * HW
                          : (cb < 194) ? f1 + (size_t)(b * 2 + (cb - 192)) * HW
                                       : f2 + (size_t)(b * 2 + (cb - 194)) * HW;
          vb = *(const float4*)(xp + gh * Ww + 4 * q);
        }
      }
      ra[it][0] = va;
      ra[it][1] = vb;
    }
  };

  auto stage_write = [&](int bufv) {
#pragma unroll
    for (int it = 0; it < 6; ++it) {
      const int tt = tid + it * 256;
      const int p2 = tt & 15;
      const int r  = (tt >> 4) % 3;
      const int q  = tt / 48;
      const float av[4] = {ra[it][0].x, ra[it][0].y, ra[it][0].z, ra[it][0].w};
      const float bv[4] = {ra[it][1].x, ra[it][1].y, ra[it][1].z, ra[it][1].w};
#pragma unroll
      for (int i = 0; i < 4; ++i) {
        half2v pk;
        pk[0] = (_Float16)av[i];
        pk[1] = (_Float16)bv[i];
        *reinterpret_cast<half2v*>(&xs[bufv][r][1 + 4 * q + i][2 * p2]) = pk;
      }
    }
  };

  // zero the p=0 / p=129 edge columns of BOTH buffers once (staging never writes them)
  for (int z = tid; z < 480; z += 256) {
    const int bb2 = z / 240;
    const int rem2 = z - bb2 * 240;
    const int r   = rem2 / 80;
    const int rem = rem2 - r * 80;
    const int p   = (rem >= 40) ? 129 : 0;
    const int ci  = (rem >= 40) ? (rem - 40) : rem;
    xs[bb2][r][p][ci] = (_Float16)0.f;
  }

  stage_load(0);
  stage_write(0);
  __syncthreads();

#pragma unroll 1
  for (int chunk = 0; chunk < 7; ++chunk) {
    const int buf = chunk & 1;
    const int ci0 = chunk * 32;
    if (chunk < 6) stage_load(chunk + 1);   // issue next chunk's globals early

#pragma unroll 1
    for (int t = 0; t < 9; ++t) {
      const int ki = (t >= 6) ? 2 : (t >= 3 ? 1 : 0);
      const int kj = t - 3 * ki;
      half8 bf[7];
      const size_t kcol = (size_t)(t * 224 + ci0 + l4 * 8);
#pragma unroll
      for (int f = 0; f < 7; ++f)
        bf[f] = *(const half8*)(Bp + (size_t)(n_base + f * 16 + l15) * 2016 + kcol);
      half8 af[4];
#pragma unroll
      for (int mf = 0; mf < 4; ++mf)
        af[mf] = *reinterpret_cast<const half8*>(&xs[buf][ki][m_base + mf * 16 + l15 + kj][l4 * 8]);
#pragma unroll
      for (int mf = 0; mf < 4; ++mf)
#pragma unroll
        for (int f = 0; f < 7; ++f)
          acc[mf][f] = __builtin_amdgcn_mfma_f32_16x16x32_f16(af[mf], bf[f], acc[mf][f], 0, 0, 0);
    }

    if (chunk < 6) stage_write(buf ^ 1);    // convert + write into the other buffer
    __syncthreads();
  }

  // epilogue: bias + 10*tanh + flow-add -> off_pm[b][hw][288]; sigmoid -> mask_pm[b][hw][144]
  const int hw0 = h * Ww;
#pragma unroll
  for (int f = 0; f < 7; ++f) {
    const int n = n_base + f * 16 + l15;
    if (n >= COFF) continue;
    const float bias = b_off[n];
    const bool isOff = (n < 288);
    const float* fl = (n < 144) ? f1 : f2;
    const size_t fladd = (size_t)(b * 2 + ((n & 1) ^ 1)) * HW;
#pragma unroll
    for (int mf = 0; mf < 4; ++mf) {
#pragma unroll
      for (int rr = 0; rr < 4; ++rr) {
        const int m = m_base + mf * 16 + l4 * 4 + rr;
        const float v = acc[mf][f][rr] + bias;
        const int p = hw0 + m;
        if (isOff) {
          off_pm[((size_t)b * HW + p) * 288 + n] = 10.f * tanhf(v) + fl[fladd + p];
        } else {
          mask_pm[((size_t)b * HW + p) * 144 + (n - 288)] = (_Float16)(1.f / (1.f + expf(-v)));
        }
      }
    }
  }
}

// ---------------- kernel 2: modulated deformable conv, 16 px/block, MFMA phase 2 ----------
// grid (8, 128, 2), block 256 (4 waves).
__global__ __launch_bounds__(256) void k_deform2(
    const _Float16* __restrict__ featT, const float* __restrict__ off_pm,
    const _Float16* __restrict__ mask_pm, const _Float16* __restrict__ wH,
    const float* __restrict__ dcb, float* __restrict__ out) {
  __shared__ __align__(16) char smem[16 * 1160 * 2];   // 37120 B
  _Float16* sm = (_Float16*)smem;                      // sm[pix][1160], j = k*128 + (g^swz)*8 + c
  float* red = (float*)smem;                           // red[w][16][66] (aliased after sync)
  const int w0  = blockIdx.x * 16;
  const int h   = blockIdx.y;
  const int b   = blockIdx.z;
  const int tid = (int)threadIdx.x;
  const int lane = tid & 63, wid = tid >> 6;
  const int l15 = lane & 15, l4 = lane >> 4;

  // ---- phase 1: gather + bilinear + mask -> LDS ----
#pragma unroll 1
  for (int i = 0; i < 9; ++i) {
    const int p   = tid + i * 256;        // 0..2303
    const int pix = p / 144;
    const int r   = p - pix * 144;
    const int g   = r / 9;
    const int k   = r - g * 9;
    const int w   = w0 + pix;
    const int hw  = h * Ww + w;
    const float2 off = *(const float2*)(off_pm + ((size_t)b * HW + hw) * 288 + 2 * r);
    const float mk = (float)mask_pm[((size_t)b * HW + hw) * 144 + r];
    const int ki = (k >= 6) ? 2 : (k >= 3 ? 1 : 0);
    const int kj = k - 3 * ki;
    const float py = (float)(h - 1 + ki) + off.x;
    const float px = (float)(w - 1 + kj) + off.y;
    const float y0f = floorf(py), x0f = floorf(px);
    const int y0 = (int)y0f, x0 = (int)x0f;
    const float ly = py - y0f, lx = px - x0f;
    const float hy = 1.f - ly, hx = 1.f - lx;
    const int y1 = y0 + 1, x1 = x0 + 1;
    const bool vy0 = (unsigned)y0 < (unsigned)Hh, vy1 = (unsigned)y1 < (unsigned)Hh;
    const bool vx0 = (unsigned)x0 < (unsigned)Ww, vx1 = (unsigned)x1 < (unsigned)Ww;
    const float w00 = (vy0 && vx0) ? hy * hx : 0.f;
    const float w01 = (vy0 && vx1) ? hy * lx : 0.f;
    const float w10 = (vy1 && vx0) ? ly * hx : 0.f;
    const float w11 = (vy1 && vx1) ? ly * lx : 0.f;
    const int cy0 = min(max(y0, 0), Hh - 1), cy1 = min(max(y1, 0), Hh - 1);
    const int cx0 = min(max(x0, 0), Ww - 1), cx1 = min(max(x1, 0), Ww - 1);
    const _Float16* gbase = featT + ((size_t)(b * 16 + g) * HW) * 8;
    const half8 s00 = *(const half8*)(gbase + (cy0 * Ww + cx0) * 8);
    const half8 s01 = *(const half8*)(gbase + (cy0 * Ww + cx1) * 8);
    const half8 s10 = *(const half8*)(gbase + (cy1 * Ww + cx0) * 8);
    const half8 s11 = *(const half8*)(gbase + (cy1 * Ww + cx1) * 8);
    half8 v = s00 * splat8(w00) + s01 * splat8(w01) + s10 * splat8(w10) + s11 * splat8(w11);
    v = v * splat8(mk);
    const int swz = (g ^ (k & 7)) << 3;
    *(half8*)(sm + pix * 1160 + k * 128 + swz) = v;
  }
  __syncthreads();

  // ---- phase 2: MFMA, K-split over 4 waves (9 steps of K=32 each) ----
  f32x4 acc[4];
#pragma unroll
  for (int nf = 0; nf < 4; ++nf) acc[nf] = (f32x4){0.f, 0.f, 0.f, 0.f};
#pragma unroll
  for (int j = 0; j < 9; ++j) {
    const int s  = wid * 9 + j;           // global K-step 0..35
    const int k  = s >> 2;                // tap
    const int cg = s & 3;                 // 32-chunk within tap
    const int gidx = cg * 4 + l4;         // logical group of this lane's 8 ci
    const half8 af = *(const half8*)(sm + l15 * 1160 + k * 128 + ((gidx ^ (k & 7)) << 3));
    const int koff = s * 32 + l4 * 8;
#pragma unroll
    for (int nf = 0; nf < 4; ++nf) {
      const half8 bf = *(const half8*)(wH + (nf * 16 + l15) * 1152 + koff);
      acc[nf] = __builtin_amdgcn_mfma_f32_16x16x32_f16(af, bf, acc[nf], 0, 0, 0);
    }
  }
  __syncthreads();   // done reading sm; alias as red
#pragma unroll
  for (int nf = 0; nf < 4; ++nf)
#pragma unroll
    for (int rr = 0; rr < 4; ++rr)
      red[(wid * 16 + l4 * 4 + rr) * 66 + nf * 16 + l15] = acc[nf][rr];
  __syncthreads();

  // ---- reduce 4 partials + bias, coalesced store ----
  const int m  = tid & 15;
  const int ng = tid >> 4;                // 0..15
#pragma unroll
  for (int i = 0; i < 4; ++i) {
    const int n = ng + 16 * i;
    float val = red[(0 * 16 + m) * 66 + n] + red[(1 * 16 + m) * 66 + n] +
                red[(2 * 16 + m) * 66 + n] + red[(3 * 16 + m) * 66 + n];
    out[(size_t)(b * 64 + n) * HW + h * Ww + w0 + m] = val + dcb[n];
  }
}

extern "C" void kernel_launch(void* const* d_in, const int* in_sizes, int n_in,
                              void* d_out, int out_size, void* d_ws, size_t ws_size,
                              hipStream_t stream) {
  const float* extra = (const float*)d_in[0];
  const float* f1    = (const float*)d_in[1];
  const float* f2    = (const float*)d_in[2];
  const float* fp    = (const float*)d_in[3];
  const float* fn2   = (const float*)d_in[4];
  const float* w_off = (const float*)d_in[5];
  const float* b_off = (const float*)d_in[6];
  const float* dcw   = (const float*)d_in[7];
  const float* dcb   = (const float*)d_in[8];
  float* out = (float*)d_out;

  // ws layout (~57.5 MB)
  float*    off_pm  = (float*)d_ws;                      // 2*HW*288 f32 = 37.7 MB
  _Float16* mask_pm = (_Float16*)(off_pm + 2 * 288 * HW);// 2*HW*144 fp16 = 9.4 MB
  _Float16* featT   = mask_pm + 2 * 144 * HW;            // 2*HW*128 fp16 = 8.4 MB
  _Float16* Bp      = featT + 2 * 128 * HW;              // 448*2016 fp16 = 1.8 MB
  _Float16* wH      = Bp + 448 * 2016;                   // 64*1152 fp16 = 0.15 MB

  hipLaunchKernelGGL(k_prep_dcw, dim3(288), dim3(256), 0, stream, dcw, wH);
  hipLaunchKernelGGL(k_prep_w, dim3((448 * 2016 + 255) / 256), dim3(256), 0, stream, w_off, Bp);
  hipLaunchKernelGGL(k_prep_feat, dim3(128), dim3(256), 0, stream, fp, fn2, featT);
  hipLaunchKernelGGL(k_offconv_mfma, dim3(128, 2, 2), dim3(256), 0, stream,
                     extra, f1, f2, Bp, b_off, off_pm, mask_pm);
  hipLaunchKernelGGL(k_deform2, dim3(8, 128, 2), dim3(256), 0, stream,
                     featT, off_pm, mask_pm, wH, dcb, out);
}